// Round 3
// baseline (167.603 us; speedup 1.0000x reference)
//
#include <hip/hip_runtime.h>
#include <hip/hip_bf16.h>

typedef short v8s __attribute__((ext_vector_type(8)));
typedef float v4f __attribute__((ext_vector_type(4)));
typedef float v16f __attribute__((ext_vector_type(16)));
typedef float v2f __attribute__((ext_vector_type(2)));

#define LN_EPS 1e-5f
#define EPS_N 1e-3f

__device__ __forceinline__ unsigned short f2bf(float f) {
    __hip_bfloat16 h = __float2bfloat16(f);
    return __builtin_bit_cast(unsigned short, h);
}
__device__ __forceinline__ unsigned int pk2(float a, float b) {
    return (unsigned)f2bf(a) | ((unsigned)f2bf(b) << 16);
}

// ---------------------------------------------------------------------------
// Fragment-linear layouts (element index, 2B elems):
//   a_f/b_f:  ((tile*8 + kb)*64 + lane)*8 + e   tile=R>>5 (R=r*32+h), lane=half*32+(R&31),
//             k = kb*16 + half*8 + e
//   w_out_f:  ((t*4 + zq)*64 + lane)*8 + e8     t=k2''>>4, zq=zh*2+e, lane=half*32+l31,
//             k2'' = t*16 + half*8 + e8, z = zh*64 + 2*l31 + e   (z-interleaved)
//             (k2'' = (h/4)*128 + k*4 + (h%4))
// ---------------------------------------------------------------------------

// k0: all outputs via coalesced READS + scatter WRITES (stores don't stall).
__global__ __launch_bounds__(256) void k0_prep(
    const float* __restrict__ mask,
    const float* __restrict__ w1, const float* __restrict__ w2,
    const float* __restrict__ w_out,
    unsigned short* __restrict__ wt,
    unsigned short* __restrict__ w_out_f,
    float* __restrict__ inv_norm) {
    const int b = blockIdx.x, t = threadIdx.x;
    // wt: coalesced read of w1/w2, scattered write. WGs 0..63, 256 elems each.
    if (b < 32) {
        const int f = b * 256 + t;          // w1 flat: f = c*32+h
        const int c = f >> 5, h = f & 31;
        wt[h * 256 + c] = f2bf(w1[f]);
    } else if (b < 64) {
        const int f = (b - 32) * 256 + t;
        const int c = f >> 5, h = f & 31;
        wt[(32 + h) * 256 + c] = f2bf(w2[f]);
    }
    // w_out_f: coalesced read w_out[f], scatter-write via inverse permutation
    #pragma unroll
    for (int e2 = 0; e2 < 2; ++e2) {
        const int f = b * 512 + e2 * 256 + t;     // f = (h*32+k)*128 + z
        const int h = f >> 12, k = (f >> 7) & 31, z = f & 127;
        const int k2 = (h >> 2) * 128 + k * 4 + (h & 3);
        const int tt = k2 >> 4, halfv = (k2 >> 3) & 1, e8 = k2 & 7;
        const int zhv = z >> 6, l31v = (z & 63) >> 1, ee = z & 1;
        const int d = (((tt * 4 + zhv * 2 + ee) * 2 + halfv) * 32 + l31v) * 8 + e8;
        w_out_f[d] = f2bf(w_out[f]);
    }
    // inv_norm row b, col t; 4-way unrolled for load ILP
    float a0 = 0.f, a1 = 0.f, a2 = 0.f, a3 = 0.f;
    #pragma unroll 4
    for (int s = 0; s < 128; s += 4) {
        a0 += mask[(s + 0) * 256 + b] * mask[(s + 0) * 256 + t];
        a1 += mask[(s + 1) * 256 + b] * mask[(s + 1) * 256 + t];
        a2 += mask[(s + 2) * 256 + b] * mask[(s + 2) * 256 + t];
        a3 += mask[(s + 3) * 256 + b] * mask[(s + 3) * 256 + t];
    }
    inv_norm[b * 256 + t] = 1.0f / (EPS_N + (a0 + a1) + (a2 + a3));
}

// ---------------------------------------------------------------------------
// k1: WG = (r, s-quarter): 32 s-rows, 4 waves x 8 rows. LN + MFMA 32x64x256,
// epilogue (+bias)*mask -> a_f/b_f fragment-linear. 1024 WGs, 4 WGs/CU.
// ---------------------------------------------------------------------------
__global__ __launch_bounds__(256, 4) void k1_lnproj(
    const float* __restrict__ m, const float* __restrict__ mask,
    const float* __restrict__ ln_w, const float* __restrict__ ln_b,
    const float* __restrict__ b1, const float* __restrict__ b2,
    const unsigned short* __restrict__ wt,
    unsigned short* __restrict__ a_f, unsigned short* __restrict__ b_f) {
    __shared__ unsigned short mh[32 * 256];   // 16 KB, chunk-swizzled
    const int r = blockIdx.x, sq = blockIdx.y;
    const int tid = threadIdx.x;
    const int w = tid >> 6, l = tid & 63;
    const int quad = l >> 4, l15 = l & 15;

    const float4 lwv = *(const float4*)(ln_w + l * 4);
    const float4 lbv = *(const float4*)(ln_b + l * 4);

    const int sg0 = sq * 32 + w * 8;
    float4 v[8];
    #pragma unroll
    for (int it = 0; it < 8; ++it)
        v[it] = *(const float4*)(m + (size_t)((sg0 + it) * 256 + r) * 256 + (l << 2));
    #pragma unroll
    for (int it = 0; it < 8; ++it) {
        const float4 x = v[it];
        float sum = x.x + x.y + x.z + x.w;
        float sq2 = x.x * x.x + x.y * x.y + x.z * x.z + x.w * x.w;
        for (int off = 32; off; off >>= 1) {
            sum += __shfl_xor(sum, off);
            sq2 += __shfl_xor(sq2, off);
        }
        const float mu   = sum * (1.f / 256.f);
        const float var  = sq2 * (1.f / 256.f) - mu * mu;
        const float rstd = rsqrtf(var + LN_EPS);
        const unsigned int p0 = pk2((x.x - mu) * rstd * lwv.x + lbv.x,
                                    (x.y - mu) * rstd * lwv.y + lbv.y);
        const unsigned int p1 = pk2((x.z - mu) * rstd * lwv.z + lbv.z,
                                    (x.w - mu) * rstd * lwv.w + lbv.w);
        const int sl = w * 8 + it;
        const int addr = sl * 256 + (((l >> 1) ^ (sl & 31)) << 3) + ((l & 1) << 2);
        *(uint2*)(&mh[addr]) = make_uint2(p0, p1);
    }
    __syncthreads();

    const int mt = w >> 1, nh = w & 1;
    v4f acc[2];
    const v4f z4 = {0.f, 0.f, 0.f, 0.f};
    acc[0] = z4; acc[1] = z4;

    const int row = mt * 16 + l15;
    #pragma unroll
    for (int kb = 0; kb < 8; ++kb) {
        const v8s af = *(const v8s*)(&mh[row * 256 + (((kb * 4 + quad) ^ (row & 31)) << 3)]);
        #pragma unroll
        for (int tn = 0; tn < 2; ++tn) {
            const v8s bf = *(const v8s*)(wt + (nh * 32 + tn * 16 + l15) * 256 + kb * 32 + quad * 8);
            acc[tn] = __builtin_amdgcn_mfma_f32_16x16x32_bf16(af, bf, acc[tn], 0, 0, 0);
        }
    }

    const int s0 = sq * 32 + mt * 16 + quad * 4;
    const int kb_s = s0 >> 4, half_s = (s0 >> 3) & 1, e0 = s0 & 7;
    float mk[4];
    #pragma unroll
    for (int u = 0; u < 4; ++u) mk[u] = mask[(s0 + u) * 256 + r];
    #pragma unroll
    for (int tn = 0; tn < 2; ++tn) {
        const int h2 = nh * 32 + tn * 16 + l15;
        const float bias = (h2 < 32) ? b1[h2] : b2[h2 - 32];
        unsigned short* dst = (h2 < 32) ? a_f : b_f;
        const int h = h2 & 31;
        const v4f f = acc[tn];
        const unsigned int q0 = pk2((f[0] + bias) * mk[0], (f[1] + bias) * mk[1]);
        const unsigned int q1 = pk2((f[2] + bias) * mk[2], (f[3] + bias) * mk[3]);
        const int addr = ((r * 8 + kb_s) * 64 + half_s * 32 + h) * 8 + e0;
        *(uint2*)(dst + addr) = make_uint2(q0, q1);
    }
}

// ---------------------------------------------------------------------------
// k2 (R3): LDS-BANDWIDTH FIX. Stage-2 roles re-partitioned to (wm in 0..1 =
// i-PAIR, wn in 0..3 = single j-tile): each j-tile ds_read by 2 waves (was 4)
// -> B LDS-reads 256->128 KB/blk/CU. Per-blk LDS-pipe budget ~6.5k -> ~5k cyc
// vs 4096 MFMA cyc/SIMD (25% MfmaUtil measured == model). aP back to 64 VGPR
// but acc2 stays [2] (32) -> peak ~250 < 256 cap, no spill (R1's spill config
// was ~286 with acc2[2][2]). + T5 setprio(1) around MFMA clusters (phase-split
// role-diverse schedule = m218b's +21-39% regime).
// Pipeline (R1/R2, kept): B 16 x 32KB sub-blocks, 2x32KB dbuf, raw s_barrier
// + counted vmcnt(4); invariant: [batch(t)(4), epi VMEM(<=8), batch(t+1)(4)]
// -> vmcnt(4) == batch(t) landed, epilogue retired, batch(t+1) flying.
// LDS: B 2x32K + P 64K + red 32K = 160 KiB. Spill tripwire: WRITE_SIZE>40MB.
// ---------------------------------------------------------------------------
#define SYNC_LGKM0 asm volatile("s_waitcnt lgkmcnt(0)" ::: "memory")
#define SYNC_VM(n) asm volatile("s_waitcnt vmcnt(" #n ")" ::: "memory")
#define BARRIER()  { __builtin_amdgcn_s_barrier(); __builtin_amdgcn_sched_barrier(0); }

__global__ __launch_bounds__(512, 2) void k2_main(
    const unsigned short* __restrict__ a_f,
    const unsigned short* __restrict__ b_f,
    const unsigned short* __restrict__ w_out_f,
    const float* __restrict__ inv_norm,
    const float* __restrict__ b_out,
    float* __restrict__ out) {
    __shared__ __align__(16) unsigned char smem[163840];
    unsigned short* Bs = (unsigned short*)smem;            // 64 KB: 2 halves x 4 j-tiles
    unsigned short* P  = (unsigned short*)(smem + 65536);  // 64 KB swizzled
    unsigned int*  red = (unsigned int*)(smem + 131072);   // 32 KB bf16-pairs

    const int g = blockIdx.x;
    const int ib = g >> 2, jq0 = (g & 3) * 16;   // 16 j-quads (4 j = 32 KB each)
    const int tid = threadIdx.x, w = tid >> 6, l = tid & 63;
    const int l31 = l & 31, half = l >> 5;
    const int wm = w >> 2, wn = w & 3;     // stage-2 roles: i-pair (0..1), j-tile (0..3)
    const int zh = w >> 2, kq = w & 3;     // stage-3 roles

    // persistent w_out fragments (128 VGPR)
    v8s wfr[16][2];
    #pragma unroll
    for (int tl = 0; tl < 16; ++tl) {
        #pragma unroll
        for (int e = 0; e < 2; ++e)
            wfr[tl][e] = *(const v8s*)(w_out_f + ((kq * 16 + tl) * 4 + zh * 2 + e) * 512 + l * 8);
    }
    // persistent A fragments: i-PAIR per wave (64 VGPR)
    v8s aP[16];
    {
        const unsigned short* ab = a_f + (size_t)(ib * 4 + wm * 2) * 4096 + l * 8;
        #pragma unroll
        for (int kb = 0; kb < 8; ++kb) {
            aP[kb]     = *(const v8s*)(ab + kb * 512);
            aP[8 + kb] = *(const v8s*)(ab + 4096 + kb * 512);
        }
    }
    const float bo0 = b_out[zh * 64 + 2 * l31];
    const float bo1 = b_out[zh * 64 + 2 * l31 + 1];

    // async-DMA one 32KB j-quad into half hsel (4 x 1KB chunks per wave)
    auto dma = [&](int q, int hsel) {
        const char* gb = (const char*)b_f + (size_t)(jq0 + q) * 32768;
        #pragma unroll
        for (int it = 0; it < 4; ++it) {
            const int c = w * 4 + it;
            __builtin_amdgcn_global_load_lds((const unsigned int*)(gb + c * 1024 + l * 16),
                                             (unsigned int*)((char*)Bs + hsel * 32768 + c * 1024), 16, 0, 0);
        }
    };
    __builtin_amdgcn_sched_barrier(0);   // pin reg-loads before prologue DMAs
    dma(0, 0);
    dma(1, 1);

    const v16f z16 = {0.f,0.f,0.f,0.f,0.f,0.f,0.f,0.f,0.f,0.f,0.f,0.f,0.f,0.f,0.f,0.f};

    // stage 2 quarter-step: aP (2 i-tiles) x ONE j-tile of the 32KB B-half
    auto stage2 = [&](int hsel) {
        v16f acc2[2];
        acc2[0] = z16; acc2[1] = z16;
        const char* Bh = (const char*)Bs + hsel * 32768;
        __builtin_amdgcn_s_setprio(1);
        #pragma unroll
        for (int kb = 0; kb < 8; ++kb) {
            const v8s b0 = *(const v8s*)(Bh + wn * 8192 + kb * 1024 + l * 16);
            acc2[0] = __builtin_amdgcn_mfma_f32_32x32x16_bf16(aP[kb],     b0, acc2[0], 0, 0, 0);
            acc2[1] = __builtin_amdgcn_mfma_f32_32x32x16_bf16(aP[8 + kb], b0, acc2[1], 0, 0, 0);
        }
        __builtin_amdgcn_s_setprio(0);
        #pragma unroll
        for (int mi = 0; mi < 2; ++mi) {
            const int p = (wm * 2 + mi) * 8 + hsel * 4 + wn;
            const int esw = 2 * (p & 15);
            const v16f f = acc2[mi];
            #pragma unroll
            for (int q = 0; q < 4; ++q) {
                const unsigned int lo = pk2(f[4 * q + 0], f[4 * q + 1]);
                const unsigned int hi = pk2(f[4 * q + 2], f[4 * q + 3]);
                const int u8 = (2 * q + half) * 32 + l31;
                *(uint2*)(P + p * 1024 + ((u8 ^ esw) << 2)) = make_uint2(lo, hi);
            }
        }
    };

    // stage 3: P-LDS x wfr regs -> red partials
    auto stage3 = [&]() {
        v16f acc3[2];
        acc3[0] = z16; acc3[1] = z16;
        __builtin_amdgcn_s_setprio(1);
        #pragma unroll
        for (int tl = 0; tl < 16; ++tl) {
            const int t2 = kq * 16 + tl;
            const int u8 = t2 * 4 + half * 2;
            const v8s pa = *(const v8s*)(P + l31 * 1024 + ((u8 ^ (2 * (l31 & 15))) << 2));
            acc3[0] = __builtin_amdgcn_mfma_f32_32x32x16_bf16(pa, wfr[tl][0], acc3[0], 0, 0, 0);
            acc3[1] = __builtin_amdgcn_mfma_f32_32x32x16_bf16(pa, wfr[tl][1], acc3[1], 0, 0, 0);
        }
        __builtin_amdgcn_s_setprio(0);
        #pragma unroll
        for (int q = 0; q < 4; ++q) {
            #pragma unroll
            for (int u = 0; u < 4; ++u) {
                const int rr = 4 * q + u;
                const int p = u + 8 * q + 4 * half;
                red[w * 1024 + p * 32 + l31] = pk2(acc3[0][rr], acc3[1][rr]);
            }
        }
    };

    auto epilogue = [&](int jbx) {
        const int pq = w & 3;
        #pragma unroll
        for (int pi = 0; pi < 4; ++pi) {
            const int p = pq * 8 + half * 4 + pi;
            const int gi = ib * 4 + (p >> 3);
            const int gj = jbx * 8 + (p & 7);
            const float inv = inv_norm[gi * 256 + gj];
            float s0 = 0.f, s1 = 0.f;
            #pragma unroll
            for (int kk = 0; kk < 4; ++kk) {
                const unsigned int u = red[(zh * 4 + kk) * 1024 + p * 32 + l31];
                s0 += __builtin_bit_cast(float, u << 16);
                s1 += __builtin_bit_cast(float, u & 0xffff0000u);
            }
            v2f res;
            res.x = (s0 + bo0) * inv;
            res.y = (s1 + bo1) * inv;
            __builtin_nontemporal_store(res,
                (v2f*)(out + (size_t)(gi * 256 + gj) * 128 + zh * 64) + l31);
        }
    };

    #pragma unroll 1
    for (int blk = 0; blk < 8; ++blk) {
        // ---- even sub-block t=2*blk: B half 0 (j 0..3 of this block) ----
        SYNC_LGKM0;            // publish prev stage3 red writes
        SYNC_VM(4);            // batch(2*blk) landed; batch(2*blk+1) stays in flight
        BARRIER();
        stage2(0);
        if (blk > 0) epilogue((g & 3) * 8 + blk - 1);   // in stage-2 shadow
        SYNC_LGKM0;            // P half + red reads complete
        BARRIER();             // B half 0 free
        if (blk < 7) dma(2 * blk + 2, 0);

        // ---- odd sub-block t=2*blk+1: B half 1 (j 4..7) ----
        SYNC_LGKM0;
        if (blk < 7) { SYNC_VM(4); } else { SYNC_VM(0); }   // tail: nothing newer in flight
        BARRIER();
        stage2(1);
        SYNC_LGKM0;            // P complete
        BARRIER();             // B half 1 free; P published to all waves
        if (blk < 7) dma(2 * blk + 3, 1);
        stage3();
    }
    SYNC_LGKM0;
    BARRIER();
    epilogue((g & 3) * 8 + 7);
}

extern "C" void kernel_launch(void* const* d_in, const int* in_sizes, int n_in,
                              void* d_out, int out_size, void* d_ws, size_t ws_size,
                              hipStream_t stream) {
    const float* m     = (const float*)d_in[0];
    const float* mask  = (const float*)d_in[1];
    const float* ln_w  = (const float*)d_in[2];
    const float* ln_b  = (const float*)d_in[3];
    const float* w1    = (const float*)d_in[4];
    const float* b1    = (const float*)d_in[5];
    const float* w2    = (const float*)d_in[6];
    const float* b2    = (const float*)d_in[7];
    const float* w_out = (const float*)d_in[8];
    const float* b_out = (const float*)d_in[9];
    float* out = (float*)d_out;

    unsigned short* a_f      = (unsigned short*)d_ws;          // 2 MB
    unsigned short* b_f      = a_f + 8192 * 128;               // 2 MB
    unsigned short* w_out_f  = b_f + 8192 * 128;               // 256 KB
    float*          inv_norm = (float*)(w_out_f + 128 * 1024); // 256 KB
    unsigned short* wt       = (unsigned short*)(inv_norm + 65536); // 32 KB

    k0_prep<<<256, 256, 0, stream>>>(mask, w1, w2, w_out, wt, w_out_f, inv_norm);
    k1_lnproj<<<dim3(256, 4), 256, 0, stream>>>(m, mask, ln_w, ln_b, b1, b2, wt, a_f, b_f);
    k2_main<<<256, 512, 0, stream>>>(a_f, b_f, w_out_f, inv_norm, b_out, out);
}

// Round 4
// 149.256 us; speedup vs baseline: 1.1229x; 1.1229x over previous
//
#include <hip/hip_runtime.h>
#include <hip/hip_bf16.h>

typedef short v8s __attribute__((ext_vector_type(8)));
typedef float v4f __attribute__((ext_vector_type(4)));
typedef float v16f __attribute__((ext_vector_type(16)));
typedef float v2f __attribute__((ext_vector_type(2)));

#define LN_EPS 1e-5f
#define EPS_N 1e-3f

__device__ __forceinline__ unsigned short f2bf(float f) {
    __hip_bfloat16 h = __float2bfloat16(f);
    return __builtin_bit_cast(unsigned short, h);
}
__device__ __forceinline__ unsigned int pk2(float a, float b) {
    return (unsigned)f2bf(a) | ((unsigned)f2bf(b) << 16);
}

// ---------------------------------------------------------------------------
// Fragment-linear layouts (element index, 2B elems):
//   a_f/b_f:  ((tile*8 + kb)*64 + lane)*8 + e   tile=R>>5 (R=r*32+h), lane=half*32+(R&31),
//             k = kb*16 + half*8 + e
//   w_out_f:  ((t*4 + zq)*64 + lane)*8 + e8     t=k2''>>4, zq=zh*2+e, lane=half*32+l31,
//             k2'' = t*16 + half*8 + e8, z = zh*64 + 2*l31 + e   (z-interleaved)
//             (k2'' = (h/4)*128 + k*4 + (h%4))
// ---------------------------------------------------------------------------

// k0: all outputs via coalesced READS + scatter WRITES (stores don't stall).
__global__ __launch_bounds__(256) void k0_prep(
    const float* __restrict__ mask,
    const float* __restrict__ w1, const float* __restrict__ w2,
    const float* __restrict__ w_out,
    unsigned short* __restrict__ wt,
    unsigned short* __restrict__ w_out_f,
    float* __restrict__ inv_norm) {
    const int b = blockIdx.x, t = threadIdx.x;
    // wt: coalesced read of w1/w2, scattered write. WGs 0..63, 256 elems each.
    if (b < 32) {
        const int f = b * 256 + t;          // w1 flat: f = c*32+h
        const int c = f >> 5, h = f & 31;
        wt[h * 256 + c] = f2bf(w1[f]);
    } else if (b < 64) {
        const int f = (b - 32) * 256 + t;
        const int c = f >> 5, h = f & 31;
        wt[(32 + h) * 256 + c] = f2bf(w2[f]);
    }
    // w_out_f: coalesced read w_out[f], scatter-write via inverse permutation
    #pragma unroll
    for (int e2 = 0; e2 < 2; ++e2) {
        const int f = b * 512 + e2 * 256 + t;     // f = (h*32+k)*128 + z
        const int h = f >> 12, k = (f >> 7) & 31, z = f & 127;
        const int k2 = (h >> 2) * 128 + k * 4 + (h & 3);
        const int tt = k2 >> 4, halfv = (k2 >> 3) & 1, e8 = k2 & 7;
        const int zhv = z >> 6, l31v = (z & 63) >> 1, ee = z & 1;
        const int d = (((tt * 4 + zhv * 2 + ee) * 2 + halfv) * 32 + l31v) * 8 + e8;
        w_out_f[d] = f2bf(w_out[f]);
    }
    // inv_norm row b, col t; 4-way unrolled for load ILP
    float a0 = 0.f, a1 = 0.f, a2 = 0.f, a3 = 0.f;
    #pragma unroll 4
    for (int s = 0; s < 128; s += 4) {
        a0 += mask[(s + 0) * 256 + b] * mask[(s + 0) * 256 + t];
        a1 += mask[(s + 1) * 256 + b] * mask[(s + 1) * 256 + t];
        a2 += mask[(s + 2) * 256 + b] * mask[(s + 2) * 256 + t];
        a3 += mask[(s + 3) * 256 + b] * mask[(s + 3) * 256 + t];
    }
    inv_norm[b * 256 + t] = 1.0f / (EPS_N + (a0 + a1) + (a2 + a3));
}

// ---------------------------------------------------------------------------
// k1: WG = (r, s-quarter): 32 s-rows, 4 waves x 8 rows. LN + MFMA 32x64x256,
// epilogue (+bias)*mask -> a_f/b_f fragment-linear. 1024 WGs, 4 WGs/CU.
// ---------------------------------------------------------------------------
__global__ __launch_bounds__(256, 4) void k1_lnproj(
    const float* __restrict__ m, const float* __restrict__ mask,
    const float* __restrict__ ln_w, const float* __restrict__ ln_b,
    const float* __restrict__ b1, const float* __restrict__ b2,
    const unsigned short* __restrict__ wt,
    unsigned short* __restrict__ a_f, unsigned short* __restrict__ b_f) {
    __shared__ unsigned short mh[32 * 256];   // 16 KB, chunk-swizzled
    const int r = blockIdx.x, sq = blockIdx.y;
    const int tid = threadIdx.x;
    const int w = tid >> 6, l = tid & 63;
    const int quad = l >> 4, l15 = l & 15;

    const float4 lwv = *(const float4*)(ln_w + l * 4);
    const float4 lbv = *(const float4*)(ln_b + l * 4);

    const int sg0 = sq * 32 + w * 8;
    float4 v[8];
    #pragma unroll
    for (int it = 0; it < 8; ++it)
        v[it] = *(const float4*)(m + (size_t)((sg0 + it) * 256 + r) * 256 + (l << 2));
    #pragma unroll
    for (int it = 0; it < 8; ++it) {
        const float4 x = v[it];
        float sum = x.x + x.y + x.z + x.w;
        float sq2 = x.x * x.x + x.y * x.y + x.z * x.z + x.w * x.w;
        for (int off = 32; off; off >>= 1) {
            sum += __shfl_xor(sum, off);
            sq2 += __shfl_xor(sq2, off);
        }
        const float mu   = sum * (1.f / 256.f);
        const float var  = sq2 * (1.f / 256.f) - mu * mu;
        const float rstd = rsqrtf(var + LN_EPS);
        const unsigned int p0 = pk2((x.x - mu) * rstd * lwv.x + lbv.x,
                                    (x.y - mu) * rstd * lwv.y + lbv.y);
        const unsigned int p1 = pk2((x.z - mu) * rstd * lwv.z + lbv.z,
                                    (x.w - mu) * rstd * lwv.w + lbv.w);
        const int sl = w * 8 + it;
        const int addr = sl * 256 + (((l >> 1) ^ (sl & 31)) << 3) + ((l & 1) << 2);
        *(uint2*)(&mh[addr]) = make_uint2(p0, p1);
    }
    __syncthreads();

    const int mt = w >> 1, nh = w & 1;
    v4f acc[2];
    const v4f z4 = {0.f, 0.f, 0.f, 0.f};
    acc[0] = z4; acc[1] = z4;

    const int row = mt * 16 + l15;
    #pragma unroll
    for (int kb = 0; kb < 8; ++kb) {
        const v8s af = *(const v8s*)(&mh[row * 256 + (((kb * 4 + quad) ^ (row & 31)) << 3)]);
        #pragma unroll
        for (int tn = 0; tn < 2; ++tn) {
            const v8s bf = *(const v8s*)(wt + (nh * 32 + tn * 16 + l15) * 256 + kb * 32 + quad * 8);
            acc[tn] = __builtin_amdgcn_mfma_f32_16x16x32_bf16(af, bf, acc[tn], 0, 0, 0);
        }
    }

    const int s0 = sq * 32 + mt * 16 + quad * 4;
    const int kb_s = s0 >> 4, half_s = (s0 >> 3) & 1, e0 = s0 & 7;
    float mk[4];
    #pragma unroll
    for (int u = 0; u < 4; ++u) mk[u] = mask[(s0 + u) * 256 + r];
    #pragma unroll
    for (int tn = 0; tn < 2; ++tn) {
        const int h2 = nh * 32 + tn * 16 + l15;
        const float bias = (h2 < 32) ? b1[h2] : b2[h2 - 32];
        unsigned short* dst = (h2 < 32) ? a_f : b_f;
        const int h = h2 & 31;
        const v4f f = acc[tn];
        const unsigned int q0 = pk2((f[0] + bias) * mk[0], (f[1] + bias) * mk[1]);
        const unsigned int q1 = pk2((f[2] + bias) * mk[2], (f[3] + bias) * mk[3]);
        const int addr = ((r * 8 + kb_s) * 64 + half_s * 32 + h) * 8 + e0;
        *(uint2*)(dst + addr) = make_uint2(q0, q1);
    }
}

// ---------------------------------------------------------------------------
// k2 (R4): EXACT R2 STRUCTURE (proven 53.5 us, no spill: aP=32 VGPR, wm=i-tile
// 0..3, wn=j-pair 0..1) + ONE isolated delta: T5 s_setprio(1) around MFMA
// clusters. R3's ledger lesson: wfr(128)+aP(64) spills (WRITE_SIZE 51.7MB,
// cold-dispatch 160us scratch-alloc fingerprint); aP must stay 32.
// Pipeline: B 16 x 32KB sub-blocks, 2x32KB dbuf, raw s_barrier + counted
// vmcnt(4); invariant: [batch(t)(4), epi VMEM(<=8), batch(t+1)(4)] ->
// vmcnt(4) == batch(t) landed, epilogue retired, batch(t+1) flying.
// LDS: B 2x32K + P 64K + red 32K = 160 KiB.
// Tripwire: WRITE_SIZE > 40MB => spill returned.
// ---------------------------------------------------------------------------
#define SYNC_LGKM0 asm volatile("s_waitcnt lgkmcnt(0)" ::: "memory")
#define SYNC_VM(n) asm volatile("s_waitcnt vmcnt(" #n ")" ::: "memory")
#define BARRIER()  { __builtin_amdgcn_s_barrier(); __builtin_amdgcn_sched_barrier(0); }

__global__ __launch_bounds__(512, 2) void k2_main(
    const unsigned short* __restrict__ a_f,
    const unsigned short* __restrict__ b_f,
    const unsigned short* __restrict__ w_out_f,
    const float* __restrict__ inv_norm,
    const float* __restrict__ b_out,
    float* __restrict__ out) {
    __shared__ __align__(16) unsigned char smem[163840];
    unsigned short* Bs = (unsigned short*)smem;            // 64 KB: 2 halves x 4 j-tiles
    unsigned short* P  = (unsigned short*)(smem + 65536);  // 64 KB swizzled
    unsigned int*  red = (unsigned int*)(smem + 131072);   // 32 KB bf16-pairs

    const int g = blockIdx.x;
    const int ib = g >> 2, jq0 = (g & 3) * 16;   // 16 j-quads (4 j = 32 KB each)
    const int tid = threadIdx.x, w = tid >> 6, l = tid & 63;
    const int l31 = l & 31, half = l >> 5;
    const int wm = w >> 1, wn = w & 1;     // stage-2 roles: i-tile (0..3), j-pair (0..1)
    const int zh = w >> 2, kq = w & 3;     // stage-3 roles

    // persistent w_out fragments (128 VGPR)
    v8s wfr[16][2];
    #pragma unroll
    for (int tl = 0; tl < 16; ++tl) {
        #pragma unroll
        for (int e = 0; e < 2; ++e)
            wfr[tl][e] = *(const v8s*)(w_out_f + ((kq * 16 + tl) * 4 + zh * 2 + e) * 512 + l * 8);
    }
    // persistent A fragments: ONE i-tile per wave (32 VGPR — spill-safe cap)
    v8s aP[8];
    {
        const unsigned short* ab = a_f + (size_t)(ib * 4 + wm) * 4096 + l * 8;
        #pragma unroll
        for (int kb = 0; kb < 8; ++kb)
            aP[kb] = *(const v8s*)(ab + kb * 512);
    }
    const float bo0 = b_out[zh * 64 + 2 * l31];
    const float bo1 = b_out[zh * 64 + 2 * l31 + 1];

    // async-DMA one 32KB j-quad into half hsel (4 x 1KB chunks per wave)
    auto dma = [&](int q, int hsel) {
        const char* gb = (const char*)b_f + (size_t)(jq0 + q) * 32768;
        #pragma unroll
        for (int it = 0; it < 4; ++it) {
            const int c = w * 4 + it;
            __builtin_amdgcn_global_load_lds((const unsigned int*)(gb + c * 1024 + l * 16),
                                             (unsigned int*)((char*)Bs + hsel * 32768 + c * 1024), 16, 0, 0);
        }
    };
    __builtin_amdgcn_sched_barrier(0);   // pin reg-loads before prologue DMAs
    dma(0, 0);
    dma(1, 1);

    const v16f z16 = {0.f,0.f,0.f,0.f,0.f,0.f,0.f,0.f,0.f,0.f,0.f,0.f,0.f,0.f,0.f,0.f};

    // stage 2 quarter-step: aP (1 i-tile) x two j-tiles of one 32KB B-half
    auto stage2 = [&](int hsel) {
        v16f acc2[2];
        acc2[0] = z16; acc2[1] = z16;
        const char* Bh = (const char*)Bs + hsel * 32768;
        __builtin_amdgcn_s_setprio(1);
        #pragma unroll
        for (int kb = 0; kb < 8; ++kb) {
            const v8s b0 = *(const v8s*)(Bh + (wn * 2 + 0) * 8192 + kb * 1024 + l * 16);
            const v8s b1 = *(const v8s*)(Bh + (wn * 2 + 1) * 8192 + kb * 1024 + l * 16);
            acc2[0] = __builtin_amdgcn_mfma_f32_32x32x16_bf16(aP[kb], b0, acc2[0], 0, 0, 0);
            acc2[1] = __builtin_amdgcn_mfma_f32_32x32x16_bf16(aP[kb], b1, acc2[1], 0, 0, 0);
        }
        __builtin_amdgcn_s_setprio(0);
        #pragma unroll
        for (int nj = 0; nj < 2; ++nj) {
            const int p = wm * 8 + hsel * 4 + wn * 2 + nj;
            const int esw = 2 * (p & 15);
            const v16f f = acc2[nj];
            #pragma unroll
            for (int q = 0; q < 4; ++q) {
                const unsigned int lo = pk2(f[4 * q + 0], f[4 * q + 1]);
                const unsigned int hi = pk2(f[4 * q + 2], f[4 * q + 3]);
                const int u8 = (2 * q + half) * 32 + l31;
                *(uint2*)(P + p * 1024 + ((u8 ^ esw) << 2)) = make_uint2(lo, hi);
            }
        }
    };

    // stage 3: P-LDS x wfr regs -> red partials
    auto stage3 = [&]() {
        v16f acc3[2];
        acc3[0] = z16; acc3[1] = z16;
        __builtin_amdgcn_s_setprio(1);
        #pragma unroll
        for (int tl = 0; tl < 16; ++tl) {
            const int t2 = kq * 16 + tl;
            const int u8 = t2 * 4 + half * 2;
            const v8s pa = *(const v8s*)(P + l31 * 1024 + ((u8 ^ (2 * (l31 & 15))) << 2));
            acc3[0] = __builtin_amdgcn_mfma_f32_32x32x16_bf16(pa, wfr[tl][0], acc3[0], 0, 0, 0);
            acc3[1] = __builtin_amdgcn_mfma_f32_32x32x16_bf16(pa, wfr[tl][1], acc3[1], 0, 0, 0);
        }
        __builtin_amdgcn_s_setprio(0);
        #pragma unroll
        for (int q = 0; q < 4; ++q) {
            #pragma unroll
            for (int u = 0; u < 4; ++u) {
                const int rr = 4 * q + u;
                const int p = u + 8 * q + 4 * half;
                red[w * 1024 + p * 32 + l31] = pk2(acc3[0][rr], acc3[1][rr]);
            }
        }
    };

    auto epilogue = [&](int jbx) {
        const int pq = w & 3;
        #pragma unroll
        for (int pi = 0; pi < 4; ++pi) {
            const int p = pq * 8 + half * 4 + pi;
            const int gi = ib * 4 + (p >> 3);
            const int gj = jbx * 8 + (p & 7);
            const float inv = inv_norm[gi * 256 + gj];
            float s0 = 0.f, s1 = 0.f;
            #pragma unroll
            for (int kk = 0; kk < 4; ++kk) {
                const unsigned int u = red[(zh * 4 + kk) * 1024 + p * 32 + l31];
                s0 += __builtin_bit_cast(float, u << 16);
                s1 += __builtin_bit_cast(float, u & 0xffff0000u);
            }
            v2f res;
            res.x = (s0 + bo0) * inv;
            res.y = (s1 + bo1) * inv;
            __builtin_nontemporal_store(res,
                (v2f*)(out + (size_t)(gi * 256 + gj) * 128 + zh * 64) + l31);
        }
    };

    #pragma unroll 1
    for (int blk = 0; blk < 8; ++blk) {
        // ---- even sub-block t=2*blk: B half 0 (j 0..3 of this block) ----
        SYNC_LGKM0;            // publish prev stage3 red writes
        SYNC_VM(4);            // batch(2*blk) landed; batch(2*blk+1) stays in flight
        BARRIER();
        stage2(0);
        if (blk > 0) epilogue((g & 3) * 8 + blk - 1);   // in stage-2 shadow
        SYNC_LGKM0;            // P half + red reads complete
        BARRIER();             // B half 0 free
        if (blk < 7) dma(2 * blk + 2, 0);

        // ---- odd sub-block t=2*blk+1: B half 1 (j 4..7) ----
        SYNC_LGKM0;
        if (blk < 7) { SYNC_VM(4); } else { SYNC_VM(0); }   // tail: nothing newer in flight
        BARRIER();
        stage2(1);
        SYNC_LGKM0;            // P complete
        BARRIER();             // B half 1 free; P published to all waves
        if (blk < 7) dma(2 * blk + 3, 1);
        stage3();
    }
    SYNC_LGKM0;
    BARRIER();
    epilogue((g & 3) * 8 + 7);
}

extern "C" void kernel_launch(void* const* d_in, const int* in_sizes, int n_in,
                              void* d_out, int out_size, void* d_ws, size_t ws_size,
                              hipStream_t stream) {
    const float* m     = (const float*)d_in[0];
    const float* mask  = (const float*)d_in[1];
    const float* ln_w  = (const float*)d_in[2];
    const float* ln_b  = (const float*)d_in[3];
    const float* w1    = (const float*)d_in[4];
    const float* b1    = (const float*)d_in[5];
    const float* w2    = (const float*)d_in[6];
    const float* b2    = (const float*)d_in[7];
    const float* w_out = (const float*)d_in[8];
    const float* b_out = (const float*)d_in[9];
    float* out = (float*)d_out;

    unsigned short* a_f      = (unsigned short*)d_ws;          // 2 MB
    unsigned short* b_f      = a_f + 8192 * 128;               // 2 MB
    unsigned short* w_out_f  = b_f + 8192 * 128;               // 256 KB
    float*          inv_norm = (float*)(w_out_f + 128 * 1024); // 256 KB
    unsigned short* wt       = (unsigned short*)(inv_norm + 65536); // 32 KB

    k0_prep<<<256, 256, 0, stream>>>(mask, w1, w2, w_out, wt, w_out_f, inv_norm);
    k1_lnproj<<<dim3(256, 4), 256, 0, stream>>>(m, mask, ln_w, ln_b, b1, b2, wt, a_f, b_f);
    k2_main<<<256, 512, 0, stream>>>(a_f, b_f, w_out_f, inv_norm, b_out, out);
}

// Round 5
// 149.090 us; speedup vs baseline: 1.1242x; 1.0011x over previous
//
#include <hip/hip_runtime.h>
#include <hip/hip_bf16.h>

typedef short v8s __attribute__((ext_vector_type(8)));
typedef float v4f __attribute__((ext_vector_type(4)));
typedef float v16f __attribute__((ext_vector_type(16)));
typedef float v2f __attribute__((ext_vector_type(2)));

#define LN_EPS 1e-5f
#define EPS_N 1e-3f

__device__ __forceinline__ unsigned short f2bf(float f) {
    __hip_bfloat16 h = __float2bfloat16(f);
    return __builtin_bit_cast(unsigned short, h);
}
__device__ __forceinline__ unsigned int pk2(float a, float b) {
    return (unsigned)f2bf(a) | ((unsigned)f2bf(b) << 16);
}

// ---------------------------------------------------------------------------
// Fragment-linear layouts (element index, 2B elems):
//   a_f/b_f:  ((tile*8 + kb)*64 + lane)*8 + e   tile=R>>5 (R=r*32+h), lane=half*32+(R&31),
//             k = kb*16 + half*8 + e
//   w_out_f:  ((t*4 + zq)*64 + lane)*8 + e8     t=k2''>>4, zq=zh*2+e, lane=half*32+l31,
//             k2'' = t*16 + half*8 + e8, z = zh*64 + 2*l31 + e   (z-interleaved)
//             (k2'' = (h/4)*128 + k*4 + (h%4))
// ---------------------------------------------------------------------------

// k0: all outputs via coalesced READS + scatter WRITES (stores don't stall).
__global__ __launch_bounds__(256) void k0_prep(
    const float* __restrict__ mask,
    const float* __restrict__ w1, const float* __restrict__ w2,
    const float* __restrict__ w_out,
    unsigned short* __restrict__ wt,
    unsigned short* __restrict__ w_out_f,
    float* __restrict__ inv_norm) {
    const int b = blockIdx.x, t = threadIdx.x;
    // wt: coalesced read of w1/w2, scattered write. WGs 0..63, 256 elems each.
    if (b < 32) {
        const int f = b * 256 + t;          // w1 flat: f = c*32+h
        const int c = f >> 5, h = f & 31;
        wt[h * 256 + c] = f2bf(w1[f]);
    } else if (b < 64) {
        const int f = (b - 32) * 256 + t;
        const int c = f >> 5, h = f & 31;
        wt[(32 + h) * 256 + c] = f2bf(w2[f]);
    }
    // w_out_f: coalesced read w_out[f], scatter-write via inverse permutation
    #pragma unroll
    for (int e2 = 0; e2 < 2; ++e2) {
        const int f = b * 512 + e2 * 256 + t;     // f = (h*32+k)*128 + z
        const int h = f >> 12, k = (f >> 7) & 31, z = f & 127;
        const int k2 = (h >> 2) * 128 + k * 4 + (h & 3);
        const int tt = k2 >> 4, halfv = (k2 >> 3) & 1, e8 = k2 & 7;
        const int zhv = z >> 6, l31v = (z & 63) >> 1, ee = z & 1;
        const int d = (((tt * 4 + zhv * 2 + ee) * 2 + halfv) * 32 + l31v) * 8 + e8;
        w_out_f[d] = f2bf(w_out[f]);
    }
    // inv_norm row b, col t; 4-way unrolled for load ILP
    float a0 = 0.f, a1 = 0.f, a2 = 0.f, a3 = 0.f;
    #pragma unroll 4
    for (int s = 0; s < 128; s += 4) {
        a0 += mask[(s + 0) * 256 + b] * mask[(s + 0) * 256 + t];
        a1 += mask[(s + 1) * 256 + b] * mask[(s + 1) * 256 + t];
        a2 += mask[(s + 2) * 256 + b] * mask[(s + 2) * 256 + t];
        a3 += mask[(s + 3) * 256 + b] * mask[(s + 3) * 256 + t];
    }
    inv_norm[b * 256 + t] = 1.0f / (EPS_N + (a0 + a1) + (a2 + a3));
}

// ---------------------------------------------------------------------------
// k1: WG = (r, s-quarter): 32 s-rows, 4 waves x 8 rows. LN + MFMA 32x64x256,
// epilogue (+bias)*mask -> a_f/b_f fragment-linear. 1024 WGs, 4 WGs/CU.
// ---------------------------------------------------------------------------
__global__ __launch_bounds__(256, 4) void k1_lnproj(
    const float* __restrict__ m, const float* __restrict__ mask,
    const float* __restrict__ ln_w, const float* __restrict__ ln_b,
    const float* __restrict__ b1, const float* __restrict__ b2,
    const unsigned short* __restrict__ wt,
    unsigned short* __restrict__ a_f, unsigned short* __restrict__ b_f) {
    __shared__ unsigned short mh[32 * 256];   // 16 KB, chunk-swizzled
    const int r = blockIdx.x, sq = blockIdx.y;
    const int tid = threadIdx.x;
    const int w = tid >> 6, l = tid & 63;
    const int quad = l >> 4, l15 = l & 15;

    const float4 lwv = *(const float4*)(ln_w + l * 4);
    const float4 lbv = *(const float4*)(ln_b + l * 4);

    const int sg0 = sq * 32 + w * 8;
    float4 v[8];
    #pragma unroll
    for (int it = 0; it < 8; ++it)
        v[it] = *(const float4*)(m + (size_t)((sg0 + it) * 256 + r) * 256 + (l << 2));
    #pragma unroll
    for (int it = 0; it < 8; ++it) {
        const float4 x = v[it];
        float sum = x.x + x.y + x.z + x.w;
        float sq2 = x.x * x.x + x.y * x.y + x.z * x.z + x.w * x.w;
        for (int off = 32; off; off >>= 1) {
            sum += __shfl_xor(sum, off);
            sq2 += __shfl_xor(sq2, off);
        }
        const float mu   = sum * (1.f / 256.f);
        const float var  = sq2 * (1.f / 256.f) - mu * mu;
        const float rstd = rsqrtf(var + LN_EPS);
        const unsigned int p0 = pk2((x.x - mu) * rstd * lwv.x + lbv.x,
                                    (x.y - mu) * rstd * lwv.y + lbv.y);
        const unsigned int p1 = pk2((x.z - mu) * rstd * lwv.z + lbv.z,
                                    (x.w - mu) * rstd * lwv.w + lbv.w);
        const int sl = w * 8 + it;
        const int addr = sl * 256 + (((l >> 1) ^ (sl & 31)) << 3) + ((l & 1) << 2);
        *(uint2*)(&mh[addr]) = make_uint2(p0, p1);
    }
    __syncthreads();

    const int mt = w >> 1, nh = w & 1;
    v4f acc[2];
    const v4f z4 = {0.f, 0.f, 0.f, 0.f};
    acc[0] = z4; acc[1] = z4;

    const int row = mt * 16 + l15;
    #pragma unroll
    for (int kb = 0; kb < 8; ++kb) {
        const v8s af = *(const v8s*)(&mh[row * 256 + (((kb * 4 + quad) ^ (row & 31)) << 3)]);
        #pragma unroll
        for (int tn = 0; tn < 2; ++tn) {
            const v8s bf = *(const v8s*)(wt + (nh * 32 + tn * 16 + l15) * 256 + kb * 32 + quad * 8);
            acc[tn] = __builtin_amdgcn_mfma_f32_16x16x32_bf16(af, bf, acc[tn], 0, 0, 0);
        }
    }

    const int s0 = sq * 32 + mt * 16 + quad * 4;
    const int kb_s = s0 >> 4, half_s = (s0 >> 3) & 1, e0 = s0 & 7;
    float mk[4];
    #pragma unroll
    for (int u = 0; u < 4; ++u) mk[u] = mask[(s0 + u) * 256 + r];
    #pragma unroll
    for (int tn = 0; tn < 2; ++tn) {
        const int h2 = nh * 32 + tn * 16 + l15;
        const float bias = (h2 < 32) ? b1[h2] : b2[h2 - 32];
        unsigned short* dst = (h2 < 32) ? a_f : b_f;
        const int h = h2 & 31;
        const v4f f = acc[tn];
        const unsigned int q0 = pk2((f[0] + bias) * mk[0], (f[1] + bias) * mk[1]);
        const unsigned int q1 = pk2((f[2] + bias) * mk[2], (f[3] + bias) * mk[3]);
        const int addr = ((r * 8 + kb_s) * 64 + half_s * 32 + h) * 8 + e0;
        *(uint2*)(dst + addr) = make_uint2(q0, q1);
    }
}

// ---------------------------------------------------------------------------
// k2 (R5): WAIT-STRUCTURE RELAXATION on the proven R4 kernel (45.0 us).
// Three provable over-waits removed (queue traced per-wave, in-order vmcnt):
//  1. top-odd vmcnt(4) -> vmcnt(12): queue there is [batch(2n+1)(4), epi
//     NT-stores(8), batch(2n+2)(4)]; landing batch(2n+1) needs only "retire
//     oldest 4". vm(4) forced full HBM completion of all 8 output stores
//     every blk. (blk0: no epi yet -> vm(4); blk7: no dma after bar2 -> vm(8))
//  2. lgkm0 before bar2 removed: s2(0)'s P ds_writes need draining only at
//     bar4 (before s3's P reads) -- "memory" clobber there pins them.
//  3. lgkm0 at top-odd removed (vacuous: epi red-reads are retired by data
//     dep before their dependent stores; DMA is vmcnt-only).
// Epilogue-red race check: epi(n-1) red-reads retire before their dependent
// stores (issued pre-bar2); s3(n) overwrites red only after bar4 -> safe.
// Everything else identical to R4 (aP=32 cap, T5 setprio, 2x32K B dbuf,
// counted vmcnt). LDS: B 64K + P 64K + red 32K = 160 KiB.
// Tripwire: WRITE_SIZE > 40MB => spill returned.
// ---------------------------------------------------------------------------
#define SYNC_LGKM0 asm volatile("s_waitcnt lgkmcnt(0)" ::: "memory")
#define SYNC_VM(n) asm volatile("s_waitcnt vmcnt(" #n ")" ::: "memory")
#define BARRIER()  { __builtin_amdgcn_s_barrier(); __builtin_amdgcn_sched_barrier(0); }

__global__ __launch_bounds__(512, 2) void k2_main(
    const unsigned short* __restrict__ a_f,
    const unsigned short* __restrict__ b_f,
    const unsigned short* __restrict__ w_out_f,
    const float* __restrict__ inv_norm,
    const float* __restrict__ b_out,
    float* __restrict__ out) {
    __shared__ __align__(16) unsigned char smem[163840];
    unsigned short* Bs = (unsigned short*)smem;            // 64 KB: 2 halves x 4 j-tiles
    unsigned short* P  = (unsigned short*)(smem + 65536);  // 64 KB swizzled
    unsigned int*  red = (unsigned int*)(smem + 131072);   // 32 KB bf16-pairs

    const int g = blockIdx.x;
    const int ib = g >> 2, jq0 = (g & 3) * 16;   // 16 j-quads (4 j = 32 KB each)
    const int tid = threadIdx.x, w = tid >> 6, l = tid & 63;
    const int l31 = l & 31, half = l >> 5;
    const int wm = w >> 1, wn = w & 1;     // stage-2 roles: i-tile (0..3), j-pair (0..1)
    const int zh = w >> 2, kq = w & 3;     // stage-3 roles

    // persistent w_out fragments (128 VGPR)
    v8s wfr[16][2];
    #pragma unroll
    for (int tl = 0; tl < 16; ++tl) {
        #pragma unroll
        for (int e = 0; e < 2; ++e)
            wfr[tl][e] = *(const v8s*)(w_out_f + ((kq * 16 + tl) * 4 + zh * 2 + e) * 512 + l * 8);
    }
    // persistent A fragments: ONE i-tile per wave (32 VGPR — spill-safe cap)
    v8s aP[8];
    {
        const unsigned short* ab = a_f + (size_t)(ib * 4 + wm) * 4096 + l * 8;
        #pragma unroll
        for (int kb = 0; kb < 8; ++kb)
            aP[kb] = *(const v8s*)(ab + kb * 512);
    }
    const float bo0 = b_out[zh * 64 + 2 * l31];
    const float bo1 = b_out[zh * 64 + 2 * l31 + 1];

    // async-DMA one 32KB j-quad into half hsel (4 x 1KB chunks per wave)
    auto dma = [&](int q, int hsel) {
        const char* gb = (const char*)b_f + (size_t)(jq0 + q) * 32768;
        #pragma unroll
        for (int it = 0; it < 4; ++it) {
            const int c = w * 4 + it;
            __builtin_amdgcn_global_load_lds((const unsigned int*)(gb + c * 1024 + l * 16),
                                             (unsigned int*)((char*)Bs + hsel * 32768 + c * 1024), 16, 0, 0);
        }
    };
    __builtin_amdgcn_sched_barrier(0);   // pin reg-loads before prologue DMAs (vm-count stability)
    dma(0, 0);
    dma(1, 1);

    const v16f z16 = {0.f,0.f,0.f,0.f,0.f,0.f,0.f,0.f,0.f,0.f,0.f,0.f,0.f,0.f,0.f,0.f};

    // stage 2 quarter-step: aP (1 i-tile) x two j-tiles of one 32KB B-half
    auto stage2 = [&](int hsel) {
        v16f acc2[2];
        acc2[0] = z16; acc2[1] = z16;
        const char* Bh = (const char*)Bs + hsel * 32768;
        __builtin_amdgcn_s_setprio(1);
        #pragma unroll
        for (int kb = 0; kb < 8; ++kb) {
            const v8s b0 = *(const v8s*)(Bh + (wn * 2 + 0) * 8192 + kb * 1024 + l * 16);
            const v8s b1 = *(const v8s*)(Bh + (wn * 2 + 1) * 8192 + kb * 1024 + l * 16);
            acc2[0] = __builtin_amdgcn_mfma_f32_32x32x16_bf16(aP[kb], b0, acc2[0], 0, 0, 0);
            acc2[1] = __builtin_amdgcn_mfma_f32_32x32x16_bf16(aP[kb], b1, acc2[1], 0, 0, 0);
        }
        __builtin_amdgcn_s_setprio(0);
        #pragma unroll
        for (int nj = 0; nj < 2; ++nj) {
            const int p = wm * 8 + hsel * 4 + wn * 2 + nj;
            const int esw = 2 * (p & 15);
            const v16f f = acc2[nj];
            #pragma unroll
            for (int q = 0; q < 4; ++q) {
                const unsigned int lo = pk2(f[4 * q + 0], f[4 * q + 1]);
                const unsigned int hi = pk2(f[4 * q + 2], f[4 * q + 3]);
                const int u8 = (2 * q + half) * 32 + l31;
                *(uint2*)(P + p * 1024 + ((u8 ^ esw) << 2)) = make_uint2(lo, hi);
            }
        }
    };

    // stage 3: P-LDS x wfr regs -> red partials
    auto stage3 = [&]() {
        v16f acc3[2];
        acc3[0] = z16; acc3[1] = z16;
        __builtin_amdgcn_s_setprio(1);
        #pragma unroll
        for (int tl = 0; tl < 16; ++tl) {
            const int t2 = kq * 16 + tl;
            const int u8 = t2 * 4 + half * 2;
            const v8s pa = *(const v8s*)(P + l31 * 1024 + ((u8 ^ (2 * (l31 & 15))) << 2));
            acc3[0] = __builtin_amdgcn_mfma_f32_32x32x16_bf16(pa, wfr[tl][0], acc3[0], 0, 0, 0);
            acc3[1] = __builtin_amdgcn_mfma_f32_32x32x16_bf16(pa, wfr[tl][1], acc3[1], 0, 0, 0);
        }
        __builtin_amdgcn_s_setprio(0);
        #pragma unroll
        for (int q = 0; q < 4; ++q) {
            #pragma unroll
            for (int u = 0; u < 4; ++u) {
                const int rr = 4 * q + u;
                const int p = u + 8 * q + 4 * half;
                red[w * 1024 + p * 32 + l31] = pk2(acc3[0][rr], acc3[1][rr]);
            }
        }
    };

    auto epilogue = [&](int jbx) {
        const int pq = w & 3;
        #pragma unroll
        for (int pi = 0; pi < 4; ++pi) {
            const int p = pq * 8 + half * 4 + pi;
            const int gi = ib * 4 + (p >> 3);
            const int gj = jbx * 8 + (p & 7);
            const float inv = inv_norm[gi * 256 + gj];
            float s0 = 0.f, s1 = 0.f;
            #pragma unroll
            for (int kk = 0; kk < 4; ++kk) {
                const unsigned int u = red[(zh * 4 + kk) * 1024 + p * 32 + l31];
                s0 += __builtin_bit_cast(float, u << 16);
                s1 += __builtin_bit_cast(float, u & 0xffff0000u);
            }
            v2f res;
            res.x = (s0 + bo0) * inv;
            res.y = (s1 + bo1) * inv;
            __builtin_nontemporal_store(res,
                (v2f*)(out + (size_t)(gi * 256 + gj) * 128 + zh * 64) + l31);
        }
    };

    #pragma unroll 1
    for (int blk = 0; blk < 8; ++blk) {
        // ---- even sub-block t=2*blk: B half 0 (j 0..3 of this block) ----
        SYNC_LGKM0;            // publish prev stage3 red writes (readers: epilogue below)
        SYNC_VM(4);            // batch(2*blk) landed (drains older epi stores by order)
        BARRIER();
        stage2(0);
        if (blk > 0) epilogue((g & 3) * 8 + blk - 1);   // in stage-2 shadow
        BARRIER();             // B half 0 free (P-writes drain deferred to bar4)
        if (blk < 7) dma(2 * blk + 2, 0);

        // ---- odd sub-block t=2*blk+1: B half 1 (j 4..7) ----
        if (blk == 0)      { SYNC_VM(4); }    // queue: [b1(4), b2(4)] -> need b1
        else if (blk < 7)  { SYNC_VM(12); }   // [b(2n+1)(4), epi(8), b(2n+2)(4)] -> retire oldest 4
        else               { SYNC_VM(8); }    // [b15(4), epi(8)] -> need b15
        BARRIER();
        stage2(1);
        SYNC_LGKM0;            // ALL P writes (both halves) complete
        BARRIER();             // B half 1 free; P published to all waves
        if (blk < 7) dma(2 * blk + 3, 1);
        stage3();
    }
    SYNC_LGKM0;
    BARRIER();
    epilogue((g & 3) * 8 + 7);
}

extern "C" void kernel_launch(void* const* d_in, const int* in_sizes, int n_in,
                              void* d_out, int out_size, void* d_ws, size_t ws_size,
                              hipStream_t stream) {
    const float* m     = (const float*)d_in[0];
    const float* mask  = (const float*)d_in[1];
    const float* ln_w  = (const float*)d_in[2];
    const float* ln_b  = (const float*)d_in[3];
    const float* w1    = (const float*)d_in[4];
    const float* b1    = (const float*)d_in[5];
    const float* w2    = (const float*)d_in[6];
    const float* b2    = (const float*)d_in[7];
    const float* w_out = (const float*)d_in[8];
    const float* b_out = (const float*)d_in[9];
    float* out = (float*)d_out;

    unsigned short* a_f      = (unsigned short*)d_ws;          // 2 MB
    unsigned short* b_f      = a_f + 8192 * 128;               // 2 MB
    unsigned short* w_out_f  = b_f + 8192 * 128;               // 256 KB
    float*          inv_norm = (float*)(w_out_f + 128 * 1024); // 256 KB
    unsigned short* wt       = (unsigned short*)(inv_norm + 65536); // 32 KB

    k0_prep<<<256, 256, 0, stream>>>(mask, w1, w2, w_out, wt, w_out_f, inv_norm);
    k1_lnproj<<<dim3(256, 4), 256, 0, stream>>>(m, mask, ln_w, ln_b, b1, b2, wt, a_f, b_f);
    k2_main<<<256, 512, 0, stream>>>(a_f, b_f, w_out_f, inv_norm, b_out, out);
}

// Round 6
// 147.575 us; speedup vs baseline: 1.1357x; 1.0103x over previous
//
#include <hip/hip_runtime.h>
#include <hip/hip_bf16.h>

typedef short v8s __attribute__((ext_vector_type(8)));
typedef float v4f __attribute__((ext_vector_type(4)));
typedef float v16f __attribute__((ext_vector_type(16)));
typedef float v2f __attribute__((ext_vector_type(2)));

#define LN_EPS 1e-5f
#define EPS_N 1e-3f

__device__ __forceinline__ unsigned short f2bf(float f) {
    __hip_bfloat16 h = __float2bfloat16(f);
    return __builtin_bit_cast(unsigned short, h);
}
__device__ __forceinline__ unsigned int pk2(float a, float b) {
    return (unsigned)f2bf(a) | ((unsigned)f2bf(b) << 16);
}

// ---------------------------------------------------------------------------
// Fragment-linear layouts (element index, 2B elems):
//   a_f/b_f:  ((tile*8 + kb)*64 + lane)*8 + e   tile=R>>5 (R=r*32+h), lane=half*32+(R&31),
//             k = kb*16 + half*8 + e
//   w_out_f:  ((t*4 + zq)*64 + lane)*8 + e8     t=k2''>>4, zq=zh*2+e, lane=half*32+l31,
//             k2'' = t*16 + half*8 + e8, z = zh*64 + 2*l31 + e   (z-interleaved)
//             (k2'' = (h/4)*128 + k*4 + (h%4))
// ---------------------------------------------------------------------------

// k0: all outputs via coalesced READS + scatter WRITES (stores don't stall).
__global__ __launch_bounds__(256) void k0_prep(
    const float* __restrict__ mask,
    const float* __restrict__ w1, const float* __restrict__ w2,
    const float* __restrict__ w_out,
    unsigned short* __restrict__ wt,
    unsigned short* __restrict__ w_out_f,
    float* __restrict__ inv_norm) {
    const int b = blockIdx.x, t = threadIdx.x;
    // wt: coalesced read of w1/w2, scattered write. WGs 0..63, 256 elems each.
    if (b < 32) {
        const int f = b * 256 + t;          // w1 flat: f = c*32+h
        const int c = f >> 5, h = f & 31;
        wt[h * 256 + c] = f2bf(w1[f]);
    } else if (b < 64) {
        const int f = (b - 32) * 256 + t;
        const int c = f >> 5, h = f & 31;
        wt[(32 + h) * 256 + c] = f2bf(w2[f]);
    }
    // w_out_f: coalesced read w_out[f], scatter-write via inverse permutation
    #pragma unroll
    for (int e2 = 0; e2 < 2; ++e2) {
        const int f = b * 512 + e2 * 256 + t;     // f = (h*32+k)*128 + z
        const int h = f >> 12, k = (f >> 7) & 31, z = f & 127;
        const int k2 = (h >> 2) * 128 + k * 4 + (h & 3);
        const int tt = k2 >> 4, halfv = (k2 >> 3) & 1, e8 = k2 & 7;
        const int zhv = z >> 6, l31v = (z & 63) >> 1, ee = z & 1;
        const int d = (((tt * 4 + zhv * 2 + ee) * 2 + halfv) * 32 + l31v) * 8 + e8;
        w_out_f[d] = f2bf(w_out[f]);
    }
    // inv_norm row b, col t; 4-way unrolled for load ILP
    float a0 = 0.f, a1 = 0.f, a2 = 0.f, a3 = 0.f;
    #pragma unroll 4
    for (int s = 0; s < 128; s += 4) {
        a0 += mask[(s + 0) * 256 + b] * mask[(s + 0) * 256 + t];
        a1 += mask[(s + 1) * 256 + b] * mask[(s + 1) * 256 + t];
        a2 += mask[(s + 2) * 256 + b] * mask[(s + 2) * 256 + t];
        a3 += mask[(s + 3) * 256 + b] * mask[(s + 3) * 256 + t];
    }
    inv_norm[b * 256 + t] = 1.0f / (EPS_N + (a0 + a1) + (a2 + a3));
}

// ---------------------------------------------------------------------------
// k1: WG = (r, s-quarter): 32 s-rows, 4 waves x 8 rows. LN + MFMA 32x64x256,
// epilogue (+bias)*mask -> a_f/b_f fragment-linear. 1024 WGs, 4 WGs/CU.
// ---------------------------------------------------------------------------
__global__ __launch_bounds__(256, 4) void k1_lnproj(
    const float* __restrict__ m, const float* __restrict__ mask,
    const float* __restrict__ ln_w, const float* __restrict__ ln_b,
    const float* __restrict__ b1, const float* __restrict__ b2,
    const unsigned short* __restrict__ wt,
    unsigned short* __restrict__ a_f, unsigned short* __restrict__ b_f) {
    __shared__ unsigned short mh[32 * 256];   // 16 KB, chunk-swizzled
    const int r = blockIdx.x, sq = blockIdx.y;
    const int tid = threadIdx.x;
    const int w = tid >> 6, l = tid & 63;
    const int quad = l >> 4, l15 = l & 15;

    const float4 lwv = *(const float4*)(ln_w + l * 4);
    const float4 lbv = *(const float4*)(ln_b + l * 4);

    const int sg0 = sq * 32 + w * 8;
    float4 v[8];
    #pragma unroll
    for (int it = 0; it < 8; ++it)
        v[it] = *(const float4*)(m + (size_t)((sg0 + it) * 256 + r) * 256 + (l << 2));
    #pragma unroll
    for (int it = 0; it < 8; ++it) {
        const float4 x = v[it];
        float sum = x.x + x.y + x.z + x.w;
        float sq2 = x.x * x.x + x.y * x.y + x.z * x.z + x.w * x.w;
        for (int off = 32; off; off >>= 1) {
            sum += __shfl_xor(sum, off);
            sq2 += __shfl_xor(sq2, off);
        }
        const float mu   = sum * (1.f / 256.f);
        const float var  = sq2 * (1.f / 256.f) - mu * mu;
        const float rstd = rsqrtf(var + LN_EPS);
        const unsigned int p0 = pk2((x.x - mu) * rstd * lwv.x + lbv.x,
                                    (x.y - mu) * rstd * lwv.y + lbv.y);
        const unsigned int p1 = pk2((x.z - mu) * rstd * lwv.z + lbv.z,
                                    (x.w - mu) * rstd * lwv.w + lbv.w);
        const int sl = w * 8 + it;
        const int addr = sl * 256 + (((l >> 1) ^ (sl & 31)) << 3) + ((l & 1) << 2);
        *(uint2*)(&mh[addr]) = make_uint2(p0, p1);
    }
    __syncthreads();

    const int mt = w >> 1, nh = w & 1;
    v4f acc[2];
    const v4f z4 = {0.f, 0.f, 0.f, 0.f};
    acc[0] = z4; acc[1] = z4;

    const int row = mt * 16 + l15;
    #pragma unroll
    for (int kb = 0; kb < 8; ++kb) {
        const v8s af = *(const v8s*)(&mh[row * 256 + (((kb * 4 + quad) ^ (row & 31)) << 3)]);
        #pragma unroll
        for (int tn = 0; tn < 2; ++tn) {
            const v8s bf = *(const v8s*)(wt + (nh * 32 + tn * 16 + l15) * 256 + kb * 32 + quad * 8);
            acc[tn] = __builtin_amdgcn_mfma_f32_16x16x32_bf16(af, bf, acc[tn], 0, 0, 0);
        }
    }

    const int s0 = sq * 32 + mt * 16 + quad * 4;
    const int kb_s = s0 >> 4, half_s = (s0 >> 3) & 1, e0 = s0 & 7;
    float mk[4];
    #pragma unroll
    for (int u = 0; u < 4; ++u) mk[u] = mask[(s0 + u) * 256 + r];
    #pragma unroll
    for (int tn = 0; tn < 2; ++tn) {
        const int h2 = nh * 32 + tn * 16 + l15;
        const float bias = (h2 < 32) ? b1[h2] : b2[h2 - 32];
        unsigned short* dst = (h2 < 32) ? a_f : b_f;
        const int h = h2 & 31;
        const v4f f = acc[tn];
        const unsigned int q0 = pk2((f[0] + bias) * mk[0], (f[1] + bias) * mk[1]);
        const unsigned int q1 = pk2((f[2] + bias) * mk[2], (f[3] + bias) * mk[3]);
        const int addr = ((r * 8 + kb_s) * 64 + half_s * 32 + h) * 8 + e0;
        *(uint2*)(dst + addr) = make_uint2(q0, q1);
    }
}

// ---------------------------------------------------------------------------
// k2 (R6): R4 EXACTLY (proven 45.0 us) minus ONE redundant barrier.
// R5 lesson: R4's wait set is a local optimum (3-way relaxed variant lost
// 3.2 us); only equivalence-preserving transforms from here. The transform:
// R4's bar2 (B half0 free) and bar3 (batch 2n+1 published) were separated
// only by the dma-issue. Folding the batch wait BEFORE a single merged
// barrier serves both: at the merge every wave has (a) finished its s2(0)
// B-reads (data-dep retired), (b) drained P(half0) ds_writes + epi red-reads
// (lgkm0), (c) retired everything through batch(2n+1) (vm(0) == R4's
// effective drain there, since R4's vm(4) sat atop a 20-deep queue incl.
// the fresh DMA). dma(2n+2) issues after the merged barrier: ~4 instrs later
// than R4, deadline a full sub-block away (~1500 cyc slack vs ~900 cyc HBM).
// 3 barriers/blk instead of 4 (-8 s_barrier/WG).
// Everything else IDENTICAL to R4: aP=32 cap (spill wall at wfr128+aP64),
// T5 setprio, 2x32K B dbuf, counted vm(4) at top-even.
// LDS: B 64K + P 64K(32K used) + red 32K. Tripwires: WRITE_SIZE>40MB=spill;
// FETCH >> 7.4MB = L2 residency broken.
// ---------------------------------------------------------------------------
#define SYNC_LGKM0 asm volatile("s_waitcnt lgkmcnt(0)" ::: "memory")
#define SYNC_VM(n) asm volatile("s_waitcnt vmcnt(" #n ")" ::: "memory")
#define BARRIER()  { __builtin_amdgcn_s_barrier(); __builtin_amdgcn_sched_barrier(0); }

__global__ __launch_bounds__(512, 2) void k2_main(
    const unsigned short* __restrict__ a_f,
    const unsigned short* __restrict__ b_f,
    const unsigned short* __restrict__ w_out_f,
    const float* __restrict__ inv_norm,
    const float* __restrict__ b_out,
    float* __restrict__ out) {
    __shared__ __align__(16) unsigned char smem[163840];
    unsigned short* Bs = (unsigned short*)smem;            // 64 KB: 2 halves x 4 j-tiles
    unsigned short* P  = (unsigned short*)(smem + 65536);  // 64 KB swizzled
    unsigned int*  red = (unsigned int*)(smem + 131072);   // 32 KB bf16-pairs

    const int g = blockIdx.x;
    const int ib = g >> 2, jq0 = (g & 3) * 16;   // 16 j-quads (4 j = 32 KB each)
    const int tid = threadIdx.x, w = tid >> 6, l = tid & 63;
    const int l31 = l & 31, half = l >> 5;
    const int wm = w >> 1, wn = w & 1;     // stage-2 roles: i-tile (0..3), j-pair (0..1)
    const int zh = w >> 2, kq = w & 3;     // stage-3 roles

    // persistent w_out fragments (128 VGPR)
    v8s wfr[16][2];
    #pragma unroll
    for (int tl = 0; tl < 16; ++tl) {
        #pragma unroll
        for (int e = 0; e < 2; ++e)
            wfr[tl][e] = *(const v8s*)(w_out_f + ((kq * 16 + tl) * 4 + zh * 2 + e) * 512 + l * 8);
    }
    // persistent A fragments: ONE i-tile per wave (32 VGPR — spill-safe cap)
    v8s aP[8];
    {
        const unsigned short* ab = a_f + (size_t)(ib * 4 + wm) * 4096 + l * 8;
        #pragma unroll
        for (int kb = 0; kb < 8; ++kb)
            aP[kb] = *(const v8s*)(ab + kb * 512);
    }
    const float bo0 = b_out[zh * 64 + 2 * l31];
    const float bo1 = b_out[zh * 64 + 2 * l31 + 1];

    // async-DMA one 32KB j-quad into half hsel (4 x 1KB chunks per wave)
    auto dma = [&](int q, int hsel) {
        const char* gb = (const char*)b_f + (size_t)(jq0 + q) * 32768;
        #pragma unroll
        for (int it = 0; it < 4; ++it) {
            const int c = w * 4 + it;
            __builtin_amdgcn_global_load_lds((const unsigned int*)(gb + c * 1024 + l * 16),
                                             (unsigned int*)((char*)Bs + hsel * 32768 + c * 1024), 16, 0, 0);
        }
    };
    __builtin_amdgcn_sched_barrier(0);   // pin reg-loads before prologue DMAs (vm-count stability)
    dma(0, 0);
    dma(1, 1);

    const v16f z16 = {0.f,0.f,0.f,0.f,0.f,0.f,0.f,0.f,0.f,0.f,0.f,0.f,0.f,0.f,0.f,0.f};

    // stage 2 quarter-step: aP (1 i-tile) x two j-tiles of one 32KB B-half
    auto stage2 = [&](int hsel) {
        v16f acc2[2];
        acc2[0] = z16; acc2[1] = z16;
        const char* Bh = (const char*)Bs + hsel * 32768;
        __builtin_amdgcn_s_setprio(1);
        #pragma unroll
        for (int kb = 0; kb < 8; ++kb) {
            const v8s b0 = *(const v8s*)(Bh + (wn * 2 + 0) * 8192 + kb * 1024 + l * 16);
            const v8s b1 = *(const v8s*)(Bh + (wn * 2 + 1) * 8192 + kb * 1024 + l * 16);
            acc2[0] = __builtin_amdgcn_mfma_f32_32x32x16_bf16(aP[kb], b0, acc2[0], 0, 0, 0);
            acc2[1] = __builtin_amdgcn_mfma_f32_32x32x16_bf16(aP[kb], b1, acc2[1], 0, 0, 0);
        }
        __builtin_amdgcn_s_setprio(0);
        #pragma unroll
        for (int nj = 0; nj < 2; ++nj) {
            const int p = wm * 8 + hsel * 4 + wn * 2 + nj;
            const int esw = 2 * (p & 15);
            const v16f f = acc2[nj];
            #pragma unroll
            for (int q = 0; q < 4; ++q) {
                const unsigned int lo = pk2(f[4 * q + 0], f[4 * q + 1]);
                const unsigned int hi = pk2(f[4 * q + 2], f[4 * q + 3]);
                const int u8 = (2 * q + half) * 32 + l31;
                *(uint2*)(P + p * 1024 + ((u8 ^ esw) << 2)) = make_uint2(lo, hi);
            }
        }
    };

    // stage 3: P-LDS x wfr regs -> red partials
    auto stage3 = [&]() {
        v16f acc3[2];
        acc3[0] = z16; acc3[1] = z16;
        __builtin_amdgcn_s_setprio(1);
        #pragma unroll
        for (int tl = 0; tl < 16; ++tl) {
            const int t2 = kq * 16 + tl;
            const int u8 = t2 * 4 + half * 2;
            const v8s pa = *(const v8s*)(P + l31 * 1024 + ((u8 ^ (2 * (l31 & 15))) << 2));
            acc3[0] = __builtin_amdgcn_mfma_f32_32x32x16_bf16(pa, wfr[tl][0], acc3[0], 0, 0, 0);
            acc3[1] = __builtin_amdgcn_mfma_f32_32x32x16_bf16(pa, wfr[tl][1], acc3[1], 0, 0, 0);
        }
        __builtin_amdgcn_s_setprio(0);
        #pragma unroll
        for (int q = 0; q < 4; ++q) {
            #pragma unroll
            for (int u = 0; u < 4; ++u) {
                const int rr = 4 * q + u;
                const int p = u + 8 * q + 4 * half;
                red[w * 1024 + p * 32 + l31] = pk2(acc3[0][rr], acc3[1][rr]);
            }
        }
    };

    auto epilogue = [&](int jbx) {
        const int pq = w & 3;
        #pragma unroll
        for (int pi = 0; pi < 4; ++pi) {
            const int p = pq * 8 + half * 4 + pi;
            const int gi = ib * 4 + (p >> 3);
            const int gj = jbx * 8 + (p & 7);
            const float inv = inv_norm[gi * 256 + gj];
            float s0 = 0.f, s1 = 0.f;
            #pragma unroll
            for (int kk = 0; kk < 4; ++kk) {
                const unsigned int u = red[(zh * 4 + kk) * 1024 + p * 32 + l31];
                s0 += __builtin_bit_cast(float, u << 16);
                s1 += __builtin_bit_cast(float, u & 0xffff0000u);
            }
            v2f res;
            res.x = (s0 + bo0) * inv;
            res.y = (s1 + bo1) * inv;
            __builtin_nontemporal_store(res,
                (v2f*)(out + (size_t)(gi * 256 + gj) * 128 + zh * 64) + l31);
        }
    };

    #pragma unroll 1
    for (int blk = 0; blk < 8; ++blk) {
        // ---- even sub-block: B half 0 (j 0..3 of this block) ----
        SYNC_LGKM0;            // publish prev stage3 red writes (epilogue reads them)
        SYNC_VM(4);            // own chunks of batch(2*blk) landed; batch(2*blk+1) stays flying
        BARRIER();             // bar1: red published; B half 0 valid for all waves
        stage2(0);
        if (blk > 0) epilogue((g & 3) * 8 + blk - 1);   // in stage-2 shadow
        SYNC_LGKM0;            // P(half0) writes + epi red-reads drained
        SYNC_VM(0);            // batch(2*blk+1) landed (== R4 effective drain set)
        BARRIER();             // MERGED bar2+3: half0 free AND half1 published
        if (blk < 7) dma(2 * blk + 2, 0);

        // ---- odd sub-block: B half 1 (j 4..7) ----
        stage2(1);
        SYNC_LGKM0;            // ALL P writes (both halves) complete
        BARRIER();             // bar4: P published; B half 1 free
        if (blk < 7) dma(2 * blk + 3, 1);
        stage3();
    }
    SYNC_LGKM0;
    BARRIER();
    epilogue((g & 3) * 8 + 7);
}

extern "C" void kernel_launch(void* const* d_in, const int* in_sizes, int n_in,
                              void* d_out, int out_size, void* d_ws, size_t ws_size,
                              hipStream_t stream) {
    const float* m     = (const float*)d_in[0];
    const float* mask  = (const float*)d_in[1];
    const float* ln_w  = (const float*)d_in[2];
    const float* ln_b  = (const float*)d_in[3];
    const float* w1    = (const float*)d_in[4];
    const float* b1    = (const float*)d_in[5];
    const float* w2    = (const float*)d_in[6];
    const float* b2    = (const float*)d_in[7];
    const float* w_out = (const float*)d_in[8];
    const float* b_out = (const float*)d_in[9];
    float* out = (float*)d_out;

    unsigned short* a_f      = (unsigned short*)d_ws;          // 2 MB
    unsigned short* b_f      = a_f + 8192 * 128;               // 2 MB
    unsigned short* w_out_f  = b_f + 8192 * 128;               // 256 KB
    float*          inv_norm = (float*)(w_out_f + 128 * 1024); // 256 KB
    unsigned short* wt       = (unsigned short*)(inv_norm + 65536); // 32 KB

    k0_prep<<<256, 256, 0, stream>>>(mask, w1, w2, w_out, wt, w_out_f, inv_norm);
    k1_lnproj<<<dim3(256, 4), 256, 0, stream>>>(m, mask, ln_w, ln_b, b1, b2, wt, a_f, b_f);
    k2_main<<<256, 512, 0, stream>>>(a_f, b_f, w_out_f, inv_norm, b_out, out);
}